// Round 22
// baseline (395.018 us; speedup 1.0000x reference)
//
#include <hip/hip_runtime.h>
#include <math.h>

#define BN_EPS 1e-5f

typedef float v2f __attribute__((ext_vector_type(2)));

// ---------------------------------------------------------------------------
// Weight transpose (BOTH layers in one launch) into PAIR-INTERLEAVED layout:
//   k<8:  wt[q*2048 + (k>>1)*512 + co*4 + (k&1)*2 + (ci&1)]
//   k==8: wt[131072 + q*256 + co*2 + (ci&1)]
// ---------------------------------------------------------------------------
__global__ void wtrans2_kernel(const float* __restrict__ w1, float* __restrict__ wt1,
                               const float* __restrict__ w2, float* __restrict__ wt2) {
    int gi = blockIdx.x * 256 + threadIdx.x;
    const int N = 128 * 128 * 9;
    if (gi >= 2 * N) return;
    const float* w = (gi < N) ? w1 : w2;
    float* wt = (gi < N) ? wt1 : wt2;
    int i = (gi < N) ? gi : gi - N;
    int co = i / 1152;
    int rem = i - co * 1152;
    int ci = rem / 9;
    int k = rem - ci * 9;
    float v = w[i];
    int q = ci >> 1, z = ci & 1;
    if (k < 8) {
        int kk = k >> 1, h = k & 1;
        wt[q * 2048 + kk * 512 + co * 4 + h * 2 + z] = v;
    } else {
        wt[131072 + q * 256 + co * 2 + z] = v;
    }
}

// ---------------------------------------------------------------------------
// Pad+interleave x -> xpi[16][64][34][36][2] AND zero yp's borders (fused).
// ---------------------------------------------------------------------------
__global__ void prep_kernel(const float* __restrict__ x, float* __restrict__ xpi,
                            float* __restrict__ yp) {
    const int plane = blockIdx.x;            // n*64 + q, 1024 blocks
    const int n = plane >> 6, q = plane & 63;
    const float* sp0 = x + ((size_t)n * 128 + 2 * q) * 1024;
    const float* sp1 = sp0 + 1024;
    float* dp = xpi + (size_t)plane * 2448;
    for (int e = threadIdx.x; e < 2448; e += 256) {
        const int idx = e >> 1, z = e & 1;
        const int pr = idx / 36, pc = idx - pr * 36;
        const int r = pr - 1, c = pc - 1;
        float v = 0.f;
        if ((unsigned)r < 32u && (unsigned)c < 32u) v = (z ? sp1 : sp0)[r * 32 + c];
        dp[e] = v;
    }
    // zero borders of yp for the same plane index
    float* bp = yp + (size_t)plane * 2448;
    const int t = threadIdx.x;               // 200 used
    if (t < 72) { bp[t] = 0.f; bp[33 * 72 + t] = 0.f; }
    else if (t < 136) {
        int r = 1 + ((t - 72) >> 1), z = (t - 72) & 1;
        bp[r * 72 + z] = 0.f;
    } else if (t < 200) {
        int r = 1 + ((t - 136) >> 1), z = (t - 136) & 1;
        bp[r * 72 + 66 + z] = 0.f;
    }
}

// ---------------------------------------------------------------------------
// Conv helpers: packed plane-pair math.
// ---------------------------------------------------------------------------
__device__ __forceinline__ void load_rowI(v2f (&R)[10], const float* rp) {
    *(float4*)&R[0] = *(const float4*)(rp);
    *(float4*)&R[2] = *(const float4*)(rp + 4);
    *(float4*)&R[4] = *(const float4*)(rp + 8);
    *(float4*)&R[6] = *(const float4*)(rp + 12);
    *(float4*)&R[8] = *(const float4*)(rp + 16);
}

__device__ __forceinline__ void rowacc(float (&acc)[8], const v2f (&R)[10],
                                       v2f w0, v2f w1, v2f w2) {
#pragma unroll
    for (int j = 0; j < 8; ++j) {
        v2f d0 = R[j] - w0;        // v_pk_add_f32 (2 subs in 1 instr)
        v2f d1 = R[j + 1] - w1;
        v2f d2 = R[j + 2] - w2;
        acc[j] += fabsf(d0.x); acc[j] += fabsf(d0.y);   // abs = src modifier
        acc[j] += fabsf(d1.x); acc[j] += fabsf(d1.y);
        acc[j] += fabsf(d2.x); acc[j] += fabsf(d2.y);
    }
}

__device__ __forceinline__ void gl_lds16(const float* g, float* l) {
    __builtin_amdgcn_global_load_lds(
        (const __attribute__((address_space(1))) void*)g,
        (__attribute__((address_space(3))) void*)l, 16, 0, 0);
}
__device__ __forceinline__ void gl_lds4(const float* g, float* l) {
    __builtin_amdgcn_global_load_lds(
        (const __attribute__((address_space(1))) void*)g,
        (__attribute__((address_space(3))) void*)l, 4, 0, 0);
}

// ---------------------------------------------------------------------------
// AdderNet conv (3x3, pad 1), PARTIAL over half the ci range, PLANE-PAIRED.
// r14/r21 structure + WEIGHTS via global_load_lds (async global->LDS, zero
// VGPR round-trip -- r20's LDS-weights retest without its spill failure).
// Per 2-pair group: 12 async loads (3 per wave: 4x1KB width16 + 2x256B
// width4 per pair), 18KB double buffer, one barrier per group (vmcnt drain
// covered by ~900cyc of compute). Hot loop consumes weights as 5 contiguous
// ds_read_b128/b64 per pair (lane*16B, conflict-free). Rows keep r14's
// wave-uniform global float4 rotation. All 4 waves previously loaded
// IDENTICAL weights from global (4x redundant) -- now once per block.
// Grid: 2048 blocks 1D, XCD swizzle (bid&7 -> n pair).
// Block: 256 thr = 4 waves = 4 px-quads (8 px each), one co-half. lane = co.
// Output: positive partial sums, co-fastest layout [n][row][px][co].
// ---------------------------------------------------------------------------
__global__ __launch_bounds__(256, 2) void adder_conv_part(
    const float* __restrict__ src,   // INTERLEAVED PADDED [16][64][34][36][2]
    const float* __restrict__ wt,    // pair-packed weights (raw base)
    float* __restrict__ dst0, float* __restrict__ dst1) {
    const int t = threadIdx.x;
    const int lane = t & 63;
    const int wq = t >> 6;                // px quad: cols 8wq..8wq+7

    // XCD-aware decode: bid%8 = XCD (round-robin dispatch).
    const int bid = blockIdx.x;
    const int xcd = bid & 7;
    const int slot = bid >> 3;            // 0..255
    const int nbit = slot >> 7;           // 0..1
    const int rem = slot & 127;
    const int half = rem >> 6;            // ci half
    const int cohalf = (rem >> 5) & 1;
    const int row = rem & 31;
    const int n = xcd * 2 + nbit;

    const int co = (cohalf << 6) + lane;
    const int qb = half * 32;             // first pair of this half

    const float* sbase = src + ((size_t)n * 64 + qb) * 2448;

    const int offA = row * 72 + wq * 16;  // padded rows row..row+2, cols 8wq..
    const int offB = offA + 72;
    const int offC = offB + 72;

    // LDS weight buffers: [2 bufs][2 pairs][1152 floats] = 18432 B.
    // Per pair slab: 4 chunks x 256 floats (kk groups, this co-half) then
    // 128 floats k8 (floats [1024,1152)).
    __shared__ __align__(16) float wl[2][2][1152];

    // Issue this wave's 3 async weight loads for pairs (p0,p0+1) into buf.
    auto stage = [&](int buf, int p0) {
#pragma unroll
        for (int k = 0; k < 3; ++k) {
            const int i = wq * 3 + k;     // 0..11
            const int pp = i / 6, c = i % 6;
            if (c < 4) {
                const float* s = wt + (size_t)(qb + p0 + pp) * 2048 + c * 512
                                 + cohalf * 256 + lane * 4;
                gl_lds16(s, &wl[buf][pp][c * 256]);
            } else {
                const int h = c - 4;
                const float* s = wt + 131072 + (size_t)(qb + p0 + pp) * 256
                                 + cohalf * 128 + h * 64 + lane;
                gl_lds4(s, &wl[buf][pp][1024 + h * 64]);
            }
        }
    };

    float acc[8];
#pragma unroll
    for (int j = 0; j < 8; ++j) acc[j] = 0.f;

    v2f A2[10], B2[10], C2[10];

    // Prologue: stage buffer 0 (pairs 0,1) + rows of pair 0.
    stage(0, 0);
    load_rowI(A2, sbase + offA);
    load_rowI(B2, sbase + offB);
    load_rowI(C2, sbase + offC);
    __syncthreads();

#pragma unroll 1
    for (int g = 0; g < 16; ++g) {
        const bool more = (g < 15);
        if (more) stage((g + 1) & 1, 2 * (g + 1));

        const float* slab0 = &wl[g & 1][0][0];
        const float* slab1 = &wl[g & 1][1][0];

        // ---- pair 2g ----
        {
            const float4 e0 = *(const float4*)&slab0[lane * 4];
            const float4 e1 = *(const float4*)&slab0[256 + lane * 4];
            const float4 e2 = *(const float4*)&slab0[512 + lane * 4];
            const float4 e3 = *(const float4*)&slab0[768 + lane * 4];
            const float2 e4 = *(const float2*)&slab0[1024 + lane * 2];
            const int pr = 2 * g + 1;                 // rows for next pair
            const float* spn = sbase + (size_t)pr * 2448;
            rowacc(acc, A2, (v2f){e0.x, e0.y}, (v2f){e0.z, e0.w}, (v2f){e1.x, e1.y});
            load_rowI(A2, spn + offA);
            rowacc(acc, B2, (v2f){e1.z, e1.w}, (v2f){e2.x, e2.y}, (v2f){e2.z, e2.w});
            load_rowI(B2, spn + offB);
            rowacc(acc, C2, (v2f){e3.x, e3.y}, (v2f){e3.z, e3.w}, (v2f){e4.x, e4.y});
            load_rowI(C2, spn + offC);
        }
        // ---- pair 2g+1 ----
        {
            const float4 o0 = *(const float4*)&slab1[lane * 4];
            const float4 o1 = *(const float4*)&slab1[256 + lane * 4];
            const float4 o2 = *(const float4*)&slab1[512 + lane * 4];
            const float4 o3 = *(const float4*)&slab1[768 + lane * 4];
            const float2 o4 = *(const float2*)&slab1[1024 + lane * 2];
            const int pr = (2 * g + 2 < 32) ? 2 * g + 2 : 31;
            const float* spn = sbase + (size_t)pr * 2448;
            rowacc(acc, A2, (v2f){o0.x, o0.y}, (v2f){o0.z, o0.w}, (v2f){o1.x, o1.y});
            load_rowI(A2, spn + offA);
            rowacc(acc, B2, (v2f){o1.z, o1.w}, (v2f){o2.x, o2.y}, (v2f){o2.z, o2.w});
            load_rowI(B2, spn + offB);
            rowacc(acc, C2, (v2f){o3.x, o3.y}, (v2f){o3.z, o3.w}, (v2f){o4.x, o4.y});
            load_rowI(C2, spn + offC);
        }
        __syncthreads();   // publishes next buffer (vmcnt drain covered)
    }

    // Epilogue: coalesced stores, co-fastest partial layout.
    const int c0 = wq << 3;
    float* dst = half ? dst1 : dst0;
    float* dp = dst + (((size_t)n * 32 + row) * 32 + c0) * 128 + co;
#pragma unroll
    for (int j = 0; j < 8; ++j) dp[j * 128] = acc[j];
}

// ---------------------------------------------------------------------------
// Combine + transpose: partials [n][row][px][co] -> out.
// PADDED=true: write interleaved padded [n][co>>1][34][36][2] interior.
// PADDED=false: standard [n][co][32][32] + per-slice row sums into
// rs[((n*32+row)*2+th)*128+co] (mean_kernel fused away).
// out = BN(-(pA+pB)) (+ReLU).
// ---------------------------------------------------------------------------
template <bool RELU, bool PADDED>
__global__ void combine_bn_t(const float* __restrict__ pA, const float* __restrict__ pB,
                             const float* __restrict__ gamma, const float* __restrict__ beta,
                             const float* __restrict__ mean, const float* __restrict__ var,
                             float* __restrict__ out, float* __restrict__ rs) {
    const int t = threadIdx.x;
    const int row = blockIdx.x;   // 0..31
    const int n = blockIdx.y;     // 0..15
    __shared__ float tile[32 * 129];
    const size_t base = (((size_t)n * 32 + row) * 32) * 128;  // + px*128 + co

    const int co = t & 127, th = t >> 7;
    const float iv = gamma[co] * rsqrtf(var[co] + BN_EPS);
    const float bb = beta[co] - mean[co] * iv;
    float psum = 0.f;
#pragma unroll
    for (int e = 0; e < 16; ++e) {
        const int px = e * 2 + th;
        const size_t idx = base + px * 128 + co;
        float z = bb - (pA[idx] + pB[idx]) * iv;
        if (RELU) z = fmaxf(z, 0.f);
        if (!PADDED) psum += z;
        tile[px * 129 + co] = z;
    }
    if (!PADDED) rs[((size_t)(n * 32 + row) * 2 + th) * 128 + co] = psum;
    __syncthreads();
#pragma unroll
    for (int e = 0; e < 4; ++e) {
        const int qidx = e * 256 + t;        // 0..1023 = 128co x 8quads
        const int oco = qidx >> 3, q = qidx & 7;
        float4 v;
        v.x = tile[(4 * q + 0) * 129 + oco];
        v.y = tile[(4 * q + 1) * 129 + oco];
        v.z = tile[(4 * q + 2) * 129 + oco];
        v.w = tile[(4 * q + 3) * 129 + oco];
        if (PADDED) {
            float* op = &out[((((size_t)n * 64 + (oco >> 1)) * 34 + row + 1) * 36
                              + 1 + 4 * q) * 2 + (oco & 1)];
            op[0] = v.x; op[2] = v.y; op[4] = v.z; op[6] = v.w;
        } else {
            *(float4*)&out[(((size_t)n * 128 + oco) * 32 + row) * 32 + 4 * q] = v;
        }
    }
}

// ---------------------------------------------------------------------------
// SE gate: mean from rs slices, then s = sigmoid(fc2(relu(fc1(mean)+b1))+b2).
// ---------------------------------------------------------------------------
__global__ void se_kernel(const float* __restrict__ rs,
                          const float* __restrict__ fc1w, const float* __restrict__ fc1b,
                          const float* __restrict__ fc2w, const float* __restrict__ fc2b,
                          float* __restrict__ s) {
    const int n = blockIdx.x;     // 16 blocks, 128 threads
    const int t = threadIdx.x;
    __shared__ float m[128], rr[8];
    float a0 = 0.f;
    for (int j = 0; j < 64; ++j) a0 += rs[((size_t)n * 64 + j) * 128 + t];
    m[t] = a0 * (1.f / 1024.f);
    __syncthreads();
    if (t < 8) {
        float a = fc1b[t];
        for (int c2 = 0; c2 < 128; ++c2) a += fc1w[t * 128 + c2] * m[c2];
        rr[t] = fmaxf(a, 0.f);
    }
    __syncthreads();
    float a = fc2b[t];
#pragma unroll
    for (int j = 0; j < 8; ++j) a += fc2w[t * 8 + j] * rr[j];
    s[n * 128 + t] = 1.f / (1.f + expf(-a));
}

// ---------------------------------------------------------------------------
// Final: out = relu(z * s[n,c] + x), vectorized float4 (standard layouts).
// ---------------------------------------------------------------------------
__global__ void final_kernel(const float* __restrict__ z, const float* __restrict__ x,
                             const float* __restrict__ s, float* __restrict__ out) {
    const int i = blockIdx.x * 256 + threadIdx.x;   // float4 index, 524288 total
    const int plane = i >> 8;                        // 256 float4 per (n,c)
    const float sc = s[plane];
    const float4 zv = ((const float4*)z)[i];
    const float4 xv = ((const float4*)x)[i];
    float4 o;
    o.x = fmaxf(zv.x * sc + xv.x, 0.f);
    o.y = fmaxf(zv.y * sc + xv.y, 0.f);
    o.z = fmaxf(zv.z * sc + xv.z, 0.f);
    o.w = fmaxf(zv.w * sc + xv.w, 0.f);
    ((float4*)out)[i] = o;
}

// ---------------------------------------------------------------------------
extern "C" void kernel_launch(void* const* d_in, const int* in_sizes, int n_in,
                              void* d_out, int out_size, void* d_ws, size_t ws_size,
                              hipStream_t stream) {
    const float* x    = (const float*)d_in[0];
    const float* w1   = (const float*)d_in[1];
    const float* g1   = (const float*)d_in[2];
    const float* b1   = (const float*)d_in[3];
    const float* m1   = (const float*)d_in[4];
    const float* v1   = (const float*)d_in[5];
    const float* w2   = (const float*)d_in[6];
    const float* g2   = (const float*)d_in[7];
    const float* b2   = (const float*)d_in[8];
    const float* m2   = (const float*)d_in[9];
    const float* v2   = (const float*)d_in[10];
    const float* fc1w = (const float*)d_in[11];
    const float* fc1b = (const float*)d_in[12];
    const float* fc2w = (const float*)d_in[13];
    const float* fc2b = (const float*)d_in[14];
    float* out = (float*)d_out;

    float* ws    = (float*)d_ws;
    float* wt1   = ws;                   // 147456 (pair-packed)
    float* wt2   = wt1 + 147456;         // 147456
    float* xpi   = wt2 + 147456;         // 2506752 (interleaved padded x; -> z)
    float* yp    = xpi + 2506752;        // 2506752 (interleaved padded y)
    float* pA    = yp + 2506752;         // 2097152 (split-0 partial, co-fast)
    float* pB    = pA + 2097152;         // 2097152 (split-1 partial, co-fast)
    float* rs    = pB + 2097152;         // 131072 (row partial sums 16x64x128)
    float* s     = rs + 131072;          // 2048
    float* z     = xpi;                  // xpi dead after conv1 -> reuse for z

    wtrans2_kernel<<<1152, 256, 0, stream>>>(w1, wt1, w2, wt2);
    prep_kernel<<<1024, 256, 0, stream>>>(x, xpi, yp);

    dim3 tgrid(32, 16);
    // Conv1 partials -> pA/pB; combine+transpose -> yp (interleaved, +ReLU).
    adder_conv_part<<<2048, 256, 0, stream>>>(xpi, wt1, pA, pB);
    combine_bn_t<true, true ><<<tgrid, 256, 0, stream>>>(pA, pB, g1, b1, m1, v1, yp, rs);
    // Conv2 partials (src = yp) -> pA/pB; combine+transpose -> z + row sums.
    adder_conv_part<<<2048, 256, 0, stream>>>(yp, wt2, pA, pB);
    combine_bn_t<false, false><<<tgrid, 256, 0, stream>>>(pA, pB, g2, b2, m2, v2, z, rs);

    se_kernel<<<16, 128, 0, stream>>>(rs, fc1w, fc1b, fc2w, fc2b, s);
    final_kernel<<<2048, 256, 0, stream>>>(z, x, s, out);
}

// Round 23
// 341.774 us; speedup vs baseline: 1.1558x; 1.1558x over previous
//
#include <hip/hip_runtime.h>
#include <math.h>

#define BN_EPS 1e-5f

typedef float v2f __attribute__((ext_vector_type(2)));

// ---------------------------------------------------------------------------
// Weight transpose (BOTH layers in one launch) into PAIR-INTERLEAVED layout:
//   k<8:  wt[q*2048 + (k>>1)*512 + co*4 + (k&1)*2 + (ci&1)]
//   k==8: wt[131072 + q*256 + co*2 + (ci&1)]
// ---------------------------------------------------------------------------
__global__ void wtrans2_kernel(const float* __restrict__ w1, float* __restrict__ wt1,
                               const float* __restrict__ w2, float* __restrict__ wt2) {
    int gi = blockIdx.x * 256 + threadIdx.x;
    const int N = 128 * 128 * 9;
    if (gi >= 2 * N) return;
    const float* w = (gi < N) ? w1 : w2;
    float* wt = (gi < N) ? wt1 : wt2;
    int i = (gi < N) ? gi : gi - N;
    int co = i / 1152;
    int rem = i - co * 1152;
    int ci = rem / 9;
    int k = rem - ci * 9;
    float v = w[i];
    int q = ci >> 1, z = ci & 1;
    if (k < 8) {
        int kk = k >> 1, h = k & 1;
        wt[q * 2048 + kk * 512 + co * 4 + h * 2 + z] = v;
    } else {
        wt[131072 + q * 256 + co * 2 + z] = v;
    }
}

// ---------------------------------------------------------------------------
// Pad+interleave x -> xpi[16][64][34][36][2] AND zero yp's borders (fused).
// ---------------------------------------------------------------------------
__global__ void prep_kernel(const float* __restrict__ x, float* __restrict__ xpi,
                            float* __restrict__ yp) {
    const int plane = blockIdx.x;            // n*64 + q, 1024 blocks
    const int n = plane >> 6, q = plane & 63;
    const float* sp0 = x + ((size_t)n * 128 + 2 * q) * 1024;
    const float* sp1 = sp0 + 1024;
    float* dp = xpi + (size_t)plane * 2448;
    for (int e = threadIdx.x; e < 2448; e += 256) {
        const int idx = e >> 1, z = e & 1;
        const int pr = idx / 36, pc = idx - pr * 36;
        const int r = pr - 1, c = pc - 1;
        float v = 0.f;
        if ((unsigned)r < 32u && (unsigned)c < 32u) v = (z ? sp1 : sp0)[r * 32 + c];
        dp[e] = v;
    }
    // zero borders of yp for the same plane index
    float* bp = yp + (size_t)plane * 2448;
    const int t = threadIdx.x;               // 200 used
    if (t < 72) { bp[t] = 0.f; bp[33 * 72 + t] = 0.f; }
    else if (t < 136) {
        int r = 1 + ((t - 72) >> 1), z = (t - 72) & 1;
        bp[r * 72 + z] = 0.f;
    } else if (t < 200) {
        int r = 1 + ((t - 136) >> 1), z = (t - 136) & 1;
        bp[r * 72 + 66 + z] = 0.f;
    }
}

// ---------------------------------------------------------------------------
// Conv helpers: packed plane-pair math (r14 winner, byte-identical).
// ---------------------------------------------------------------------------
__device__ __forceinline__ void load_rowI(v2f (&R)[10], const float* rp) {
    *(float4*)&R[0] = *(const float4*)(rp);
    *(float4*)&R[2] = *(const float4*)(rp + 4);
    *(float4*)&R[4] = *(const float4*)(rp + 8);
    *(float4*)&R[6] = *(const float4*)(rp + 12);
    *(float4*)&R[8] = *(const float4*)(rp + 16);
}

__device__ __forceinline__ void rowacc(float (&acc)[8], const v2f (&R)[10],
                                       v2f w0, v2f w1, v2f w2) {
#pragma unroll
    for (int j = 0; j < 8; ++j) {
        v2f d0 = R[j] - w0;        // v_pk_add_f32 (2 subs in 1 instr)
        v2f d1 = R[j + 1] - w1;
        v2f d2 = R[j + 2] - w2;
        acc[j] += fabsf(d0.x); acc[j] += fabsf(d0.y);   // abs = src modifier
        acc[j] += fabsf(d1.x); acc[j] += fabsf(d1.y);
        acc[j] += fabsf(d2.x); acc[j] += fabsf(d2.y);
    }
}

// ---------------------------------------------------------------------------
// AdderNet conv (3x3, pad 1), PARTIAL over half the ci range, PLANE-PAIRED.
// EXACT r14/r21 structure (best measured: 178us/conv, 343us total; confirmed
// r14/r18/r21). Register-only hot loop, weights per-lane VGPR with rotation
// prefetch, rows wave-uniform global float4 rotation. Grid 2048 1D, XCD
// swizzle. 84 VGPR, spill-free.
// Falsified alternatives (do not retry): TLP x2 (r11), LDS-x staging (r13),
// split accumulators / phase rotation (r18), hand modulo-scheduling (r19),
// LDS-weights sync (r20, spilled) and async global_load_lds (r22, +25us:
// per-group barrier + lgkm chain costs more than 4x redundant weight loads).
// ---------------------------------------------------------------------------
__global__ __launch_bounds__(256, 2) void adder_conv_part(
    const float* __restrict__ src,   // INTERLEAVED PADDED [16][64][34][36][2]
    const float* __restrict__ wt,    // pair-packed weights
    float* __restrict__ dst0, float* __restrict__ dst1) {
    const int t = threadIdx.x;
    const int lane = t & 63;
    const int wq = t >> 6;                // px quad: cols 8wq..8wq+7

    // XCD-aware decode: bid%8 = XCD (round-robin dispatch).
    const int bid = blockIdx.x;
    const int xcd = bid & 7;
    const int slot = bid >> 3;            // 0..255
    const int nbit = slot >> 7;           // 0..1
    const int rem = slot & 127;
    const int half = rem >> 6;            // ci half
    const int cohalf = (rem >> 5) & 1;
    const int row = rem & 31;
    const int n = xcd * 2 + nbit;

    const int co = (cohalf << 6) + lane;
    const int qb = half * 32;             // first pair of this half

    const float* sbase = src + ((size_t)n * 64 + qb) * 2448;
    const float* wb  = wt + (size_t)qb * 2048 + co * 4;
    const float* wb8 = wt + 131072 + (size_t)qb * 256 + co * 2;

    const int offA = row * 72 + wq * 16;  // padded rows row..row+2, cols 8wq..
    const int offB = offA + 72;
    const int offC = offB + 72;

    float acc[8];
#pragma unroll
    for (int j = 0; j < 8; ++j) acc[j] = 0.f;

    v2f A2[10], B2[10], C2[10], wk[9];

    // Prologue: pair 0 rows + weights.
    load_rowI(A2, sbase + offA);
    load_rowI(B2, sbase + offB);
    load_rowI(C2, sbase + offC);
    {
        const float4 g0 = *(const float4*)(wb);
        const float4 g1 = *(const float4*)(wb + 512);
        const float4 g2 = *(const float4*)(wb + 1024);
        const float4 g3 = *(const float4*)(wb + 1536);
        const float2 g4 = *(const float2*)(wb8);
        wk[0] = (v2f){g0.x, g0.y}; wk[1] = (v2f){g0.z, g0.w};
        wk[2] = (v2f){g1.x, g1.y}; wk[3] = (v2f){g1.z, g1.w};
        wk[4] = (v2f){g2.x, g2.y}; wk[5] = (v2f){g2.z, g2.w};
        wk[6] = (v2f){g3.x, g3.y}; wk[7] = (v2f){g3.z, g3.w};
        wk[8] = (v2f){g4.x, g4.y};
    }

#pragma unroll 1
    for (int p = 0; p < 32; ++p) {
        const int pn = (p + 1 < 32) ? p + 1 : 31;   // clamped prefetch pair
        const float* spn = sbase + (size_t)pn * 2448;
        const float* wpn = wb + (size_t)pn * 2048;
        const float* wpn8 = wb8 + (size_t)pn * 256;

        rowacc(acc, A2, wk[0], wk[1], wk[2]);
        load_rowI(A2, spn + offA);
        const float4 g0 = *(const float4*)(wpn);
        const float4 g1 = *(const float4*)(wpn + 512);
        rowacc(acc, B2, wk[3], wk[4], wk[5]);
        load_rowI(B2, spn + offB);
        const float4 g2 = *(const float4*)(wpn + 1024);
        const float4 g3 = *(const float4*)(wpn + 1536);
        const float2 g4 = *(const float2*)(wpn8);
        rowacc(acc, C2, wk[6], wk[7], wk[8]);
        load_rowI(C2, spn + offC);
        wk[0] = (v2f){g0.x, g0.y}; wk[1] = (v2f){g0.z, g0.w};
        wk[2] = (v2f){g1.x, g1.y}; wk[3] = (v2f){g1.z, g1.w};
        wk[4] = (v2f){g2.x, g2.y}; wk[5] = (v2f){g2.z, g2.w};
        wk[6] = (v2f){g3.x, g3.y}; wk[7] = (v2f){g3.z, g3.w};
        wk[8] = (v2f){g4.x, g4.y};
    }

    // Epilogue: coalesced stores, co-fastest partial layout.
    const int c0 = wq << 3;
    float* dst = half ? dst1 : dst0;
    float* dp = dst + (((size_t)n * 32 + row) * 32 + c0) * 128 + co;
#pragma unroll
    for (int j = 0; j < 8; ++j) dp[j * 128] = acc[j];
}

// ---------------------------------------------------------------------------
// Combine + transpose: partials [n][row][px][co] -> out.
// PADDED=true: write interleaved padded [n][co>>1][34][36][2] interior.
// PADDED=false: standard [n][co][32][32] + per-slice row sums into
// rs[((n*32+row)*2+th)*128+co] (mean_kernel fused away).
// out = BN(-(pA+pB)) (+ReLU).
// ---------------------------------------------------------------------------
template <bool RELU, bool PADDED>
__global__ void combine_bn_t(const float* __restrict__ pA, const float* __restrict__ pB,
                             const float* __restrict__ gamma, const float* __restrict__ beta,
                             const float* __restrict__ mean, const float* __restrict__ var,
                             float* __restrict__ out, float* __restrict__ rs) {
    const int t = threadIdx.x;
    const int row = blockIdx.x;   // 0..31
    const int n = blockIdx.y;     // 0..15
    __shared__ float tile[32 * 129];
    const size_t base = (((size_t)n * 32 + row) * 32) * 128;  // + px*128 + co

    const int co = t & 127, th = t >> 7;
    const float iv = gamma[co] * rsqrtf(var[co] + BN_EPS);
    const float bb = beta[co] - mean[co] * iv;
    float psum = 0.f;
#pragma unroll
    for (int e = 0; e < 16; ++e) {
        const int px = e * 2 + th;
        const size_t idx = base + px * 128 + co;
        float z = bb - (pA[idx] + pB[idx]) * iv;
        if (RELU) z = fmaxf(z, 0.f);
        if (!PADDED) psum += z;
        tile[px * 129 + co] = z;
    }
    if (!PADDED) rs[((size_t)(n * 32 + row) * 2 + th) * 128 + co] = psum;
    __syncthreads();
#pragma unroll
    for (int e = 0; e < 4; ++e) {
        const int qidx = e * 256 + t;        // 0..1023 = 128co x 8quads
        const int oco = qidx >> 3, q = qidx & 7;
        float4 v;
        v.x = tile[(4 * q + 0) * 129 + oco];
        v.y = tile[(4 * q + 1) * 129 + oco];
        v.z = tile[(4 * q + 2) * 129 + oco];
        v.w = tile[(4 * q + 3) * 129 + oco];
        if (PADDED) {
            float* op = &out[((((size_t)n * 64 + (oco >> 1)) * 34 + row + 1) * 36
                              + 1 + 4 * q) * 2 + (oco & 1)];
            op[0] = v.x; op[2] = v.y; op[4] = v.z; op[6] = v.w;
        } else {
            *(float4*)&out[(((size_t)n * 128 + oco) * 32 + row) * 32 + 4 * q] = v;
        }
    }
}

// ---------------------------------------------------------------------------
// SE gate: mean from rs slices, then s = sigmoid(fc2(relu(fc1(mean)+b1))+b2).
// ---------------------------------------------------------------------------
__global__ void se_kernel(const float* __restrict__ rs,
                          const float* __restrict__ fc1w, const float* __restrict__ fc1b,
                          const float* __restrict__ fc2w, const float* __restrict__ fc2b,
                          float* __restrict__ s) {
    const int n = blockIdx.x;     // 16 blocks, 128 threads
    const int t = threadIdx.x;
    __shared__ float m[128], rr[8];
    float a0 = 0.f;
    for (int j = 0; j < 64; ++j) a0 += rs[((size_t)n * 64 + j) * 128 + t];
    m[t] = a0 * (1.f / 1024.f);
    __syncthreads();
    if (t < 8) {
        float a = fc1b[t];
        for (int c2 = 0; c2 < 128; ++c2) a += fc1w[t * 128 + c2] * m[c2];
        rr[t] = fmaxf(a, 0.f);
    }
    __syncthreads();
    float a = fc2b[t];
#pragma unroll
    for (int j = 0; j < 8; ++j) a += fc2w[t * 8 + j] * rr[j];
    s[n * 128 + t] = 1.f / (1.f + expf(-a));
}

// ---------------------------------------------------------------------------
// Final: out = relu(z * s[n,c] + x), vectorized float4 (standard layouts).
// ---------------------------------------------------------------------------
__global__ void final_kernel(const float* __restrict__ z, const float* __restrict__ x,
                             const float* __restrict__ s, float* __restrict__ out) {
    const int i = blockIdx.x * 256 + threadIdx.x;   // float4 index, 524288 total
    const int plane = i >> 8;                        // 256 float4 per (n,c)
    const float sc = s[plane];
    const float4 zv = ((const float4*)z)[i];
    const float4 xv = ((const float4*)x)[i];
    float4 o;
    o.x = fmaxf(zv.x * sc + xv.x, 0.f);
    o.y = fmaxf(zv.y * sc + xv.y, 0.f);
    o.z = fmaxf(zv.z * sc + xv.z, 0.f);
    o.w = fmaxf(zv.w * sc + xv.w, 0.f);
    ((float4*)out)[i] = o;
}

// ---------------------------------------------------------------------------
extern "C" void kernel_launch(void* const* d_in, const int* in_sizes, int n_in,
                              void* d_out, int out_size, void* d_ws, size_t ws_size,
                              hipStream_t stream) {
    const float* x    = (const float*)d_in[0];
    const float* w1   = (const float*)d_in[1];
    const float* g1   = (const float*)d_in[2];
    const float* b1   = (const float*)d_in[3];
    const float* m1   = (const float*)d_in[4];
    const float* v1   = (const float*)d_in[5];
    const float* w2   = (const float*)d_in[6];
    const float* g2   = (const float*)d_in[7];
    const float* b2   = (const float*)d_in[8];
    const float* m2   = (const float*)d_in[9];
    const float* v2   = (const float*)d_in[10];
    const float* fc1w = (const float*)d_in[11];
    const float* fc1b = (const float*)d_in[12];
    const float* fc2w = (const float*)d_in[13];
    const float* fc2b = (const float*)d_in[14];
    float* out = (float*)d_out;

    float* ws    = (float*)d_ws;
    float* wt1   = ws;                   // 147456 (pair-packed)
    float* wt2   = wt1 + 147456;         // 147456
    float* xpi   = wt2 + 147456;         // 2506752 (interleaved padded x; -> z)
    float* yp    = xpi + 2506752;        // 2506752 (interleaved padded y)
    float* pA    = yp + 2506752;         // 2097152 (split-0 partial, co-fast)
    float* pB    = pA + 2097152;         // 2097152 (split-1 partial, co-fast)
    float* rs    = pB + 2097152;         // 131072 (row partial sums 16x64x128)
    float* s     = rs + 131072;          // 2048
    float* z     = xpi;                  // xpi dead after conv1 -> reuse for z

    wtrans2_kernel<<<1152, 256, 0, stream>>>(w1, wt1, w2, wt2);
    prep_kernel<<<1024, 256, 0, stream>>>(x, xpi, yp);

    dim3 tgrid(32, 16);
    // Conv1 partials -> pA/pB; combine+transpose -> yp (interleaved, +ReLU).
    adder_conv_part<<<2048, 256, 0, stream>>>(xpi, wt1, pA, pB);
    combine_bn_t<true, true ><<<tgrid, 256, 0, stream>>>(pA, pB, g1, b1, m1, v1, yp, rs);
    // Conv2 partials (src = yp) -> pA/pB; combine+transpose -> z + row sums.
    adder_conv_part<<<2048, 256, 0, stream>>>(yp, wt2, pA, pB);
    combine_bn_t<false, false><<<tgrid, 256, 0, stream>>>(pA, pB, g2, b2, m2, v2, z, rs);

    se_kernel<<<16, 128, 0, stream>>>(rs, fc1w, fc1b, fc2w, fc2b, s);
    final_kernel<<<2048, 256, 0, stream>>>(z, x, s, out);
}

// Round 24
// 302.394 us; speedup vs baseline: 1.3063x; 1.1302x over previous
//
#include <hip/hip_runtime.h>
#include <math.h>

#define BN_EPS 1e-5f

typedef float v2f __attribute__((ext_vector_type(2)));

// ---------------------------------------------------------------------------
// Weight transpose (BOTH layers in one launch) into PAIR-INTERLEAVED layout:
//   k<8:  wt[q*2048 + (k>>1)*512 + co*4 + (k&1)*2 + (ci&1)]
//   k==8: wt[131072 + q*256 + co*2 + (ci&1)]
// ---------------------------------------------------------------------------
__global__ void wtrans2_kernel(const float* __restrict__ w1, float* __restrict__ wt1,
                               const float* __restrict__ w2, float* __restrict__ wt2) {
    int gi = blockIdx.x * 256 + threadIdx.x;
    const int N = 128 * 128 * 9;
    if (gi >= 2 * N) return;
    const float* w = (gi < N) ? w1 : w2;
    float* wt = (gi < N) ? wt1 : wt2;
    int i = (gi < N) ? gi : gi - N;
    int co = i / 1152;
    int rem = i - co * 1152;
    int ci = rem / 9;
    int k = rem - ci * 9;
    float v = w[i];
    int q = ci >> 1, z = ci & 1;
    if (k < 8) {
        int kk = k >> 1, h = k & 1;
        wt[q * 2048 + kk * 512 + co * 4 + h * 2 + z] = v;
    } else {
        wt[131072 + q * 256 + co * 2 + z] = v;
    }
}

// ---------------------------------------------------------------------------
// Pad+interleave x -> xpi[16][64][34][36][2] AND zero yp's borders (fused).
// ---------------------------------------------------------------------------
__global__ void prep_kernel(const float* __restrict__ x, float* __restrict__ xpi,
                            float* __restrict__ yp) {
    const int plane = blockIdx.x;            // n*64 + q, 1024 blocks
    const int n = plane >> 6, q = plane & 63;
    const float* sp0 = x + ((size_t)n * 128 + 2 * q) * 1024;
    const float* sp1 = sp0 + 1024;
    float* dp = xpi + (size_t)plane * 2448;
    for (int e = threadIdx.x; e < 2448; e += 256) {
        const int idx = e >> 1, z = e & 1;
        const int pr = idx / 36, pc = idx - pr * 36;
        const int r = pr - 1, c = pc - 1;
        float v = 0.f;
        if ((unsigned)r < 32u && (unsigned)c < 32u) v = (z ? sp1 : sp0)[r * 32 + c];
        dp[e] = v;
    }
    // zero borders of yp for the same plane index
    float* bp = yp + (size_t)plane * 2448;
    const int t = threadIdx.x;               // 200 used
    if (t < 72) { bp[t] = 0.f; bp[33 * 72 + t] = 0.f; }
    else if (t < 136) {
        int r = 1 + ((t - 72) >> 1), z = (t - 72) & 1;
        bp[r * 72 + z] = 0.f;
    } else if (t < 200) {
        int r = 1 + ((t - 136) >> 1), z = (t - 136) & 1;
        bp[r * 72 + 66 + z] = 0.f;
    }
}

// ---------------------------------------------------------------------------
// Conv helpers: packed plane-pair math.
// ---------------------------------------------------------------------------
__device__ __forceinline__ void load_rowI(v2f (&R)[10], const float* rp) {
    *(float4*)&R[0] = *(const float4*)(rp);
    *(float4*)&R[2] = *(const float4*)(rp + 4);
    *(float4*)&R[4] = *(const float4*)(rp + 8);
    *(float4*)&R[6] = *(const float4*)(rp + 12);
    *(float4*)&R[8] = *(const float4*)(rp + 16);
}

__device__ __forceinline__ void rowacc(float (&acc)[8], const v2f (&R)[10],
                                       v2f w0, v2f w1, v2f w2) {
#pragma unroll
    for (int j = 0; j < 8; ++j) {
        v2f d0 = R[j] - w0;        // v_pk_add_f32 (2 subs in 1 instr)
        v2f d1 = R[j + 1] - w1;
        v2f d2 = R[j + 2] - w2;
        acc[j] += fabsf(d0.x); acc[j] += fabsf(d0.y);   // abs = src modifier
        acc[j] += fabsf(d1.x); acc[j] += fabsf(d1.y);
        acc[j] += fabsf(d2.x); acc[j] += fabsf(d2.y);
    }
}

// ---------------------------------------------------------------------------
// AdderNet conv (3x3, pad 1), PARTIAL over half the ci range, PLANE-PAIRED.
// r14/r21/r23 structure + UNIFORM-ROW SCALARIZATION: row offsets are
// wave-uniform in fact (row block-uniform, wq wave-uniform) but divergent in
// the compiler's analysis (wq = tid>>6). readfirstlane makes the whole row
// address chain provably uniform -> LLVM can select s_load (SMEM) for the
// 15 row loads/pair, moving them off the vector TA path (each uniform
// global_load still costs ~4 TA cyc; per CU the TA was co-critical with
// VALU: ~720 vs ~900 cyc/pair). Rows then live in SGPRs (v_pk_add_f32
// takes one SGPR-pair operand), freeing ~60 VGPRs -> occupancy can rise.
// If the compiler declines, readfirstlane is free -> neutral (clean A/B).
// Falsified (do not retry): TLPx2, LDS-x, acc-split, phase-rotation,
// modulo-sched, LDS-weights sync+async.
// ---------------------------------------------------------------------------
__global__ __launch_bounds__(256, 2) void adder_conv_part(
    const float* __restrict__ src,   // INTERLEAVED PADDED [16][64][34][36][2]
    const float* __restrict__ wt,    // pair-packed weights
    float* __restrict__ dst0, float* __restrict__ dst1) {
    const int t = threadIdx.x;
    const int lane = t & 63;
    const int wq = t >> 6;                // px quad: cols 8wq..8wq+7

    // XCD-aware decode: bid%8 = XCD (round-robin dispatch).
    const int bid = blockIdx.x;
    const int xcd = bid & 7;
    const int slot = bid >> 3;            // 0..255
    const int nbit = slot >> 7;           // 0..1
    const int rem = slot & 127;
    const int half = rem >> 6;            // ci half
    const int cohalf = (rem >> 5) & 1;
    const int row = rem & 31;
    const int n = xcd * 2 + nbit;

    const int co = (cohalf << 6) + lane;
    const int qb = half * 32;             // first pair of this half

    const float* sbase = src + ((size_t)n * 64 + qb) * 2448;
    const float* wb  = wt + (size_t)qb * 2048 + co * 4;
    const float* wb8 = wt + 131072 + (size_t)qb * 256 + co * 2;

    // Row offsets: wave-uniform in fact; readfirstlane makes them provably
    // uniform so the row loads can select the scalar (SMEM) path.
    const int offA = __builtin_amdgcn_readfirstlane(row * 72 + wq * 16);
    const int offB = offA + 72;
    const int offC = offB + 72;

    float acc[8];
#pragma unroll
    for (int j = 0; j < 8; ++j) acc[j] = 0.f;

    v2f A2[10], B2[10], C2[10], wk[9];

    // Prologue: pair 0 rows + weights.
    load_rowI(A2, sbase + offA);
    load_rowI(B2, sbase + offB);
    load_rowI(C2, sbase + offC);
    {
        const float4 g0 = *(const float4*)(wb);
        const float4 g1 = *(const float4*)(wb + 512);
        const float4 g2 = *(const float4*)(wb + 1024);
        const float4 g3 = *(const float4*)(wb + 1536);
        const float2 g4 = *(const float2*)(wb8);
        wk[0] = (v2f){g0.x, g0.y}; wk[1] = (v2f){g0.z, g0.w};
        wk[2] = (v2f){g1.x, g1.y}; wk[3] = (v2f){g1.z, g1.w};
        wk[4] = (v2f){g2.x, g2.y}; wk[5] = (v2f){g2.z, g2.w};
        wk[6] = (v2f){g3.x, g3.y}; wk[7] = (v2f){g3.z, g3.w};
        wk[8] = (v2f){g4.x, g4.y};
    }

#pragma unroll 1
    for (int p = 0; p < 32; ++p) {
        const int pn = (p + 1 < 32) ? p + 1 : 31;   // clamped prefetch pair
        const float* spn = sbase + (size_t)pn * 2448;
        const float* wpn = wb + (size_t)pn * 2048;
        const float* wpn8 = wb8 + (size_t)pn * 256;

        rowacc(acc, A2, wk[0], wk[1], wk[2]);
        load_rowI(A2, spn + offA);
        const float4 g0 = *(const float4*)(wpn);
        const float4 g1 = *(const float4*)(wpn + 512);
        rowacc(acc, B2, wk[3], wk[4], wk[5]);
        load_rowI(B2, spn + offB);
        const float4 g2 = *(const float4*)(wpn + 1024);
        const float4 g3 = *(const float4*)(wpn + 1536);
        const float2 g4 = *(const float2*)(wpn8);
        rowacc(acc, C2, wk[6], wk[7], wk[8]);
        load_rowI(C2, spn + offC);
        wk[0] = (v2f){g0.x, g0.y}; wk[1] = (v2f){g0.z, g0.w};
        wk[2] = (v2f){g1.x, g1.y}; wk[3] = (v2f){g1.z, g1.w};
        wk[4] = (v2f){g2.x, g2.y}; wk[5] = (v2f){g2.z, g2.w};
        wk[6] = (v2f){g3.x, g3.y}; wk[7] = (v2f){g3.z, g3.w};
        wk[8] = (v2f){g4.x, g4.y};
    }

    // Epilogue: coalesced stores, co-fastest partial layout.
    const int c0 = wq << 3;
    float* dst = half ? dst1 : dst0;
    float* dp = dst + (((size_t)n * 32 + row) * 32 + c0) * 128 + co;
#pragma unroll
    for (int j = 0; j < 8; ++j) dp[j * 128] = acc[j];
}

// ---------------------------------------------------------------------------
// Combine + transpose: partials [n][row][px][co] -> out.
// PADDED=true: write interleaved padded [n][co>>1][34][36][2] interior.
// PADDED=false: standard [n][co][32][32] + per-slice row sums into
// rs[((n*32+row)*2+th)*128+co] (mean_kernel fused away).
// out = BN(-(pA+pB)) (+ReLU).
// ---------------------------------------------------------------------------
template <bool RELU, bool PADDED>
__global__ void combine_bn_t(const float* __restrict__ pA, const float* __restrict__ pB,
                             const float* __restrict__ gamma, const float* __restrict__ beta,
                             const float* __restrict__ mean, const float* __restrict__ var,
                             float* __restrict__ out, float* __restrict__ rs) {
    const int t = threadIdx.x;
    const int row = blockIdx.x;   // 0..31
    const int n = blockIdx.y;     // 0..15
    __shared__ float tile[32 * 129];
    const size_t base = (((size_t)n * 32 + row) * 32) * 128;  // + px*128 + co

    const int co = t & 127, th = t >> 7;
    const float iv = gamma[co] * rsqrtf(var[co] + BN_EPS);
    const float bb = beta[co] - mean[co] * iv;
    float psum = 0.f;
#pragma unroll
    for (int e = 0; e < 16; ++e) {
        const int px = e * 2 + th;
        const size_t idx = base + px * 128 + co;
        float z = bb - (pA[idx] + pB[idx]) * iv;
        if (RELU) z = fmaxf(z, 0.f);
        if (!PADDED) psum += z;
        tile[px * 129 + co] = z;
    }
    if (!PADDED) rs[((size_t)(n * 32 + row) * 2 + th) * 128 + co] = psum;
    __syncthreads();
#pragma unroll
    for (int e = 0; e < 4; ++e) {
        const int qidx = e * 256 + t;        // 0..1023 = 128co x 8quads
        const int oco = qidx >> 3, q = qidx & 7;
        float4 v;
        v.x = tile[(4 * q + 0) * 129 + oco];
        v.y = tile[(4 * q + 1) * 129 + oco];
        v.z = tile[(4 * q + 2) * 129 + oco];
        v.w = tile[(4 * q + 3) * 129 + oco];
        if (PADDED) {
            float* op = &out[((((size_t)n * 64 + (oco >> 1)) * 34 + row + 1) * 36
                              + 1 + 4 * q) * 2 + (oco & 1)];
            op[0] = v.x; op[2] = v.y; op[4] = v.z; op[6] = v.w;
        } else {
            *(float4*)&out[(((size_t)n * 128 + oco) * 32 + row) * 32 + 4 * q] = v;
        }
    }
}

// ---------------------------------------------------------------------------
// SE gate: mean from rs slices, then s = sigmoid(fc2(relu(fc1(mean)+b1))+b2).
// ---------------------------------------------------------------------------
__global__ void se_kernel(const float* __restrict__ rs,
                          const float* __restrict__ fc1w, const float* __restrict__ fc1b,
                          const float* __restrict__ fc2w, const float* __restrict__ fc2b,
                          float* __restrict__ s) {
    const int n = blockIdx.x;     // 16 blocks, 128 threads
    const int t = threadIdx.x;
    __shared__ float m[128], rr[8];
    float a0 = 0.f;
    for (int j = 0; j < 64; ++j) a0 += rs[((size_t)n * 64 + j) * 128 + t];
    m[t] = a0 * (1.f / 1024.f);
    __syncthreads();
    if (t < 8) {
        float a = fc1b[t];
        for (int c2 = 0; c2 < 128; ++c2) a += fc1w[t * 128 + c2] * m[c2];
        rr[t] = fmaxf(a, 0.f);
    }
    __syncthreads();
    float a = fc2b[t];
#pragma unroll
    for (int j = 0; j < 8; ++j) a += fc2w[t * 8 + j] * rr[j];
    s[n * 128 + t] = 1.f / (1.f + expf(-a));
}

// ---------------------------------------------------------------------------
// Final: out = relu(z * s[n,c] + x), vectorized float4 (standard layouts).
// ---------------------------------------------------------------------------
__global__ void final_kernel(const float* __restrict__ z, const float* __restrict__ x,
                             const float* __restrict__ s, float* __restrict__ out) {
    const int i = blockIdx.x * 256 + threadIdx.x;   // float4 index, 524288 total
    const int plane = i >> 8;                        // 256 float4 per (n,c)
    const float sc = s[plane];
    const float4 zv = ((const float4*)z)[i];
    const float4 xv = ((const float4*)x)[i];
    float4 o;
    o.x = fmaxf(zv.x * sc + xv.x, 0.f);
    o.y = fmaxf(zv.y * sc + xv.y, 0.f);
    o.z = fmaxf(zv.z * sc + xv.z, 0.f);
    o.w = fmaxf(zv.w * sc + xv.w, 0.f);
    ((float4*)out)[i] = o;
}

// ---------------------------------------------------------------------------
extern "C" void kernel_launch(void* const* d_in, const int* in_sizes, int n_in,
                              void* d_out, int out_size, void* d_ws, size_t ws_size,
                              hipStream_t stream) {
    const float* x    = (const float*)d_in[0];
    const float* w1   = (const float*)d_in[1];
    const float* g1   = (const float*)d_in[2];
    const float* b1   = (const float*)d_in[3];
    const float* m1   = (const float*)d_in[4];
    const float* v1   = (const float*)d_in[5];
    const float* w2   = (const float*)d_in[6];
    const float* g2   = (const float*)d_in[7];
    const float* b2   = (const float*)d_in[8];
    const float* m2   = (const float*)d_in[9];
    const float* v2   = (const float*)d_in[10];
    const float* fc1w = (const float*)d_in[11];
    const float* fc1b = (const float*)d_in[12];
    const float* fc2w = (const float*)d_in[13];
    const float* fc2b = (const float*)d_in[14];
    float* out = (float*)d_out;

    float* ws    = (float*)d_ws;
    float* wt1   = ws;                   // 147456 (pair-packed)
    float* wt2   = wt1 + 147456;         // 147456
    float* xpi   = wt2 + 147456;         // 2506752 (interleaved padded x; -> z)
    float* yp    = xpi + 2506752;        // 2506752 (interleaved padded y)
    float* pA    = yp + 2506752;         // 2097152 (split-0 partial, co-fast)
    float* pB    = pA + 2097152;         // 2097152 (split-1 partial, co-fast)
    float* rs    = pB + 2097152;         // 131072 (row partial sums 16x64x128)
    float* s     = rs + 131072;          // 2048
    float* z     = xpi;                  // xpi dead after conv1 -> reuse for z

    wtrans2_kernel<<<1152, 256, 0, stream>>>(w1, wt1, w2, wt2);
    prep_kernel<<<1024, 256, 0, stream>>>(x, xpi, yp);

    dim3 tgrid(32, 16);
    // Conv1 partials -> pA/pB; combine+transpose -> yp (interleaved, +ReLU).
    adder_conv_part<<<2048, 256, 0, stream>>>(xpi, wt1, pA, pB);
    combine_bn_t<true, true ><<<tgrid, 256, 0, stream>>>(pA, pB, g1, b1, m1, v1, yp, rs);
    // Conv2 partials (src = yp) -> pA/pB; combine+transpose -> z + row sums.
    adder_conv_part<<<2048, 256, 0, stream>>>(yp, wt2, pA, pB);
    combine_bn_t<false, false><<<tgrid, 256, 0, stream>>>(pA, pB, g2, b2, m2, v2, z, rs);

    se_kernel<<<16, 128, 0, stream>>>(rs, fc1w, fc1b, fc2w, fc2b, s);
    final_kernel<<<2048, 256, 0, stream>>>(z, x, s, out);
}

// Round 25
// 300.411 us; speedup vs baseline: 1.3149x; 1.0066x over previous
//
#include <hip/hip_runtime.h>
#include <math.h>

#define BN_EPS 1e-5f

typedef float v2f __attribute__((ext_vector_type(2)));

// ---------------------------------------------------------------------------
// Weight transpose (BOTH layers in one launch) into PAIR-INTERLEAVED layout:
//   k<8:  wt[q*2048 + (k>>1)*512 + co*4 + (k&1)*2 + (ci&1)]
//   k==8: wt[131072 + q*256 + co*2 + (ci&1)]
// ---------------------------------------------------------------------------
__global__ void wtrans2_kernel(const float* __restrict__ w1, float* __restrict__ wt1,
                               const float* __restrict__ w2, float* __restrict__ wt2) {
    int gi = blockIdx.x * 256 + threadIdx.x;
    const int N = 128 * 128 * 9;
    if (gi >= 2 * N) return;
    const float* w = (gi < N) ? w1 : w2;
    float* wt = (gi < N) ? wt1 : wt2;
    int i = (gi < N) ? gi : gi - N;
    int co = i / 1152;
    int rem = i - co * 1152;
    int ci = rem / 9;
    int k = rem - ci * 9;
    float v = w[i];
    int q = ci >> 1, z = ci & 1;
    if (k < 8) {
        int kk = k >> 1, h = k & 1;
        wt[q * 2048 + kk * 512 + co * 4 + h * 2 + z] = v;
    } else {
        wt[131072 + q * 256 + co * 2 + z] = v;
    }
}

// ---------------------------------------------------------------------------
// Pad+interleave x -> xpi[16][64][34][36][2] AND zero yp's borders (fused).
// ---------------------------------------------------------------------------
__global__ void prep_kernel(const float* __restrict__ x, float* __restrict__ xpi,
                            float* __restrict__ yp) {
    const int plane = blockIdx.x;            // n*64 + q, 1024 blocks
    const int n = plane >> 6, q = plane & 63;
    const float* sp0 = x + ((size_t)n * 128 + 2 * q) * 1024;
    const float* sp1 = sp0 + 1024;
    float* dp = xpi + (size_t)plane * 2448;
    for (int e = threadIdx.x; e < 2448; e += 256) {
        const int idx = e >> 1, z = e & 1;
        const int pr = idx / 36, pc = idx - pr * 36;
        const int r = pr - 1, c = pc - 1;
        float v = 0.f;
        if ((unsigned)r < 32u && (unsigned)c < 32u) v = (z ? sp1 : sp0)[r * 32 + c];
        dp[e] = v;
    }
    // zero borders of yp for the same plane index
    float* bp = yp + (size_t)plane * 2448;
    const int t = threadIdx.x;               // 200 used
    if (t < 72) { bp[t] = 0.f; bp[33 * 72 + t] = 0.f; }
    else if (t < 136) {
        int r = 1 + ((t - 72) >> 1), z = (t - 72) & 1;
        bp[r * 72 + z] = 0.f;
    } else if (t < 200) {
        int r = 1 + ((t - 136) >> 1), z = (t - 136) & 1;
        bp[r * 72 + 66 + z] = 0.f;
    }
}

// ---------------------------------------------------------------------------
// Conv helpers: packed plane-pair math.
// ---------------------------------------------------------------------------
__device__ __forceinline__ void load_rowI(v2f (&R)[10], const float* rp) {
    *(float4*)&R[0] = *(const float4*)(rp);
    *(float4*)&R[2] = *(const float4*)(rp + 4);
    *(float4*)&R[4] = *(const float4*)(rp + 8);
    *(float4*)&R[6] = *(const float4*)(rp + 12);
    *(float4*)&R[8] = *(const float4*)(rp + 16);
}

__device__ __forceinline__ void rowacc(float (&acc)[8], const v2f (&R)[10],
                                       v2f w0, v2f w1, v2f w2) {
#pragma unroll
    for (int j = 0; j < 8; ++j) {
        v2f d0 = R[j] - w0;        // v_pk_add_f32 (2 subs in 1 instr)
        v2f d1 = R[j + 1] - w1;
        v2f d2 = R[j + 2] - w2;
        acc[j] += fabsf(d0.x); acc[j] += fabsf(d0.y);   // abs = src modifier
        acc[j] += fabsf(d1.x); acc[j] += fabsf(d1.y);
        acc[j] += fabsf(d2.x); acc[j] += fabsf(d2.y);
    }
}

// ---------------------------------------------------------------------------
// AdderNet conv (3x3, pad 1), PARTIAL over half the ci range, PLANE-PAIRED.
// r24 structure (scalarized rows via readfirstlane -> s_load; conv 153us,
// VGPR 52 / SGPR 96) + 2-PAIR wkE/wkO MODULO SCHEDULE: weights for pair p+2
// load DIRECTLY into the wkE/wkO registers right after each rowacc kills
// them -- removes the ~18 v_mov g->wk copies per pair (~8% of VALU).
// This retests r19's schedule under the condition that falsified it: r19
// had VGPR 96 -> only 5 waves/SIMD (grid needs 8); with rows in SGPRs the
// same schedule fits ~56 VGPR -> 8 waves/SIMD retained.
// Falsified (do not retry): TLPx2, LDS-x, acc-split, phase-rotation,
// LDS-weights sync+async.
// Grid: 2048 blocks 1D, XCD swizzle (bid&7 -> n pair).
// Block: 256 thr = 4 waves = 4 px-quads (8 px each), one co-half. lane = co.
// Output: positive partial sums, co-fastest layout [n][row][px][co].
// ---------------------------------------------------------------------------
__global__ __launch_bounds__(256, 2) void adder_conv_part(
    const float* __restrict__ src,   // INTERLEAVED PADDED [16][64][34][36][2]
    const float* __restrict__ wt,    // pair-packed weights
    float* __restrict__ dst0, float* __restrict__ dst1) {
    const int t = threadIdx.x;
    const int lane = t & 63;
    const int wq = t >> 6;                // px quad: cols 8wq..8wq+7

    // XCD-aware decode: bid%8 = XCD (round-robin dispatch).
    const int bid = blockIdx.x;
    const int xcd = bid & 7;
    const int slot = bid >> 3;            // 0..255
    const int nbit = slot >> 7;           // 0..1
    const int rem = slot & 127;
    const int half = rem >> 6;            // ci half
    const int cohalf = (rem >> 5) & 1;
    const int row = rem & 31;
    const int n = xcd * 2 + nbit;

    const int co = (cohalf << 6) + lane;
    const int qb = half * 32;             // first pair of this half

    const float* sbase = src + ((size_t)n * 64 + qb) * 2448;
    const float* wb  = wt + (size_t)qb * 2048 + co * 4;
    const float* wb8 = wt + 131072 + (size_t)qb * 256 + co * 2;

    // Row offsets: wave-uniform in fact; readfirstlane makes them provably
    // uniform so the row loads select the scalar (SMEM) path.
    const int offA = __builtin_amdgcn_readfirstlane(row * 72 + wq * 16);
    const int offB = offA + 72;
    const int offC = offB + 72;

    float acc[8];
#pragma unroll
    for (int j = 0; j < 8; ++j) acc[j] = 0.f;

    v2f A2[10], B2[10], C2[10];
    __attribute__((aligned(16))) v2f wkE[9], wkO[9];

    // Prologue: rows of pair 0; weights of pairs 0 (wkE) and 1 (wkO).
    load_rowI(A2, sbase + offA);
    load_rowI(B2, sbase + offB);
    load_rowI(C2, sbase + offC);
    {
        *(float4*)&wkE[0] = *(const float4*)(wb);
        *(float4*)&wkE[2] = *(const float4*)(wb + 512);
        *(float4*)&wkE[4] = *(const float4*)(wb + 1024);
        *(float4*)&wkE[6] = *(const float4*)(wb + 1536);
        *(float2*)&wkE[8] = *(const float2*)(wb8);
        *(float4*)&wkO[0] = *(const float4*)(wb + 2048);
        *(float4*)&wkO[2] = *(const float4*)(wb + 2048 + 512);
        *(float4*)&wkO[4] = *(const float4*)(wb + 2048 + 1024);
        *(float4*)&wkO[6] = *(const float4*)(wb + 2048 + 1536);
        *(float2*)&wkO[8] = *(const float2*)(wb8 + 256);
    }

#pragma unroll 1
    for (int p = 0; p < 32; p += 2) {
        // ---- even sub-iter: pair p (weights wkE), rows currently pair p ----
        {
            const int pr = (p + 1 < 32) ? p + 1 : 31;   // rows for next pair
            const int pw = (p + 2 < 32) ? p + 2 : 31;   // weights 2 ahead
            const float* spn = sbase + (size_t)pr * 2448;
            const float* wpn = wb + (size_t)pw * 2048;
            rowacc(acc, A2, wkE[0], wkE[1], wkE[2]);
            load_rowI(A2, spn + offA);
            *(float4*)&wkE[0] = *(const float4*)(wpn);            // wk0,1 dead
            rowacc(acc, B2, wkE[3], wkE[4], wkE[5]);
            load_rowI(B2, spn + offB);
            *(float4*)&wkE[2] = *(const float4*)(wpn + 512);      // wk2..5 dead
            *(float4*)&wkE[4] = *(const float4*)(wpn + 1024);
            rowacc(acc, C2, wkE[6], wkE[7], wkE[8]);
            load_rowI(C2, spn + offC);
            *(float4*)&wkE[6] = *(const float4*)(wpn + 1536);     // wk6..8 dead
            *(float2*)&wkE[8] = *(const float2*)(wb8 + (size_t)pw * 256);
        }
        // ---- odd sub-iter: pair p+1 (weights wkO), rows pair p+1 ----
        {
            const int pr = (p + 2 < 32) ? p + 2 : 31;
            const int pw = (p + 3 < 32) ? p + 3 : 31;
            const float* spn = sbase + (size_t)pr * 2448;
            const float* wpn = wb + (size_t)pw * 2048;
            rowacc(acc, A2, wkO[0], wkO[1], wkO[2]);
            load_rowI(A2, spn + offA);
            *(float4*)&wkO[0] = *(const float4*)(wpn);
            rowacc(acc, B2, wkO[3], wkO[4], wkO[5]);
            load_rowI(B2, spn + offB);
            *(float4*)&wkO[2] = *(const float4*)(wpn + 512);
            *(float4*)&wkO[4] = *(const float4*)(wpn + 1024);
            rowacc(acc, C2, wkO[6], wkO[7], wkO[8]);
            load_rowI(C2, spn + offC);
            *(float4*)&wkO[6] = *(const float4*)(wpn + 1536);
            *(float2*)&wkO[8] = *(const float2*)(wb8 + (size_t)pw * 256);
        }
    }

    // Epilogue: coalesced stores, co-fastest partial layout.
    const int c0 = wq << 3;
    float* dst = half ? dst1 : dst0;
    float* dp = dst + (((size_t)n * 32 + row) * 32 + c0) * 128 + co;
#pragma unroll
    for (int j = 0; j < 8; ++j) dp[j * 128] = acc[j];
}

// ---------------------------------------------------------------------------
// Combine + transpose: partials [n][row][px][co] -> out.
// PADDED=true: write interleaved padded [n][co>>1][34][36][2] interior.
// PADDED=false: standard [n][co][32][32] + per-slice row sums into
// rs[((n*32+row)*2+th)*128+co] (mean_kernel fused away).
// out = BN(-(pA+pB)) (+ReLU).
// ---------------------------------------------------------------------------
template <bool RELU, bool PADDED>
__global__ void combine_bn_t(const float* __restrict__ pA, const float* __restrict__ pB,
                             const float* __restrict__ gamma, const float* __restrict__ beta,
                             const float* __restrict__ mean, const float* __restrict__ var,
                             float* __restrict__ out, float* __restrict__ rs) {
    const int t = threadIdx.x;
    const int row = blockIdx.x;   // 0..31
    const int n = blockIdx.y;     // 0..15
    __shared__ float tile[32 * 129];
    const size_t base = (((size_t)n * 32 + row) * 32) * 128;  // + px*128 + co

    const int co = t & 127, th = t >> 7;
    const float iv = gamma[co] * rsqrtf(var[co] + BN_EPS);
    const float bb = beta[co] - mean[co] * iv;
    float psum = 0.f;
#pragma unroll
    for (int e = 0; e < 16; ++e) {
        const int px = e * 2 + th;
        const size_t idx = base + px * 128 + co;
        float z = bb - (pA[idx] + pB[idx]) * iv;
        if (RELU) z = fmaxf(z, 0.f);
        if (!PADDED) psum += z;
        tile[px * 129 + co] = z;
    }
    if (!PADDED) rs[((size_t)(n * 32 + row) * 2 + th) * 128 + co] = psum;
    __syncthreads();
#pragma unroll
    for (int e = 0; e < 4; ++e) {
        const int qidx = e * 256 + t;        // 0..1023 = 128co x 8quads
        const int oco = qidx >> 3, q = qidx & 7;
        float4 v;
        v.x = tile[(4 * q + 0) * 129 + oco];
        v.y = tile[(4 * q + 1) * 129 + oco];
        v.z = tile[(4 * q + 2) * 129 + oco];
        v.w = tile[(4 * q + 3) * 129 + oco];
        if (PADDED) {
            float* op = &out[((((size_t)n * 64 + (oco >> 1)) * 34 + row + 1) * 36
                              + 1 + 4 * q) * 2 + (oco & 1)];
            op[0] = v.x; op[2] = v.y; op[4] = v.z; op[6] = v.w;
        } else {
            *(float4*)&out[(((size_t)n * 128 + oco) * 32 + row) * 32 + 4 * q] = v;
        }
    }
}

// ---------------------------------------------------------------------------
// SE gate: mean from rs slices, then s = sigmoid(fc2(relu(fc1(mean)+b1))+b2).
// ---------------------------------------------------------------------------
__global__ void se_kernel(const float* __restrict__ rs,
                          const float* __restrict__ fc1w, const float* __restrict__ fc1b,
                          const float* __restrict__ fc2w, const float* __restrict__ fc2b,
                          float* __restrict__ s) {
    const int n = blockIdx.x;     // 16 blocks, 128 threads
    const int t = threadIdx.x;
    __shared__ float m[128], rr[8];
    float a0 = 0.f;
    for (int j = 0; j < 64; ++j) a0 += rs[((size_t)n * 64 + j) * 128 + t];
    m[t] = a0 * (1.f / 1024.f);
    __syncthreads();
    if (t < 8) {
        float a = fc1b[t];
        for (int c2 = 0; c2 < 128; ++c2) a += fc1w[t * 128 + c2] * m[c2];
        rr[t] = fmaxf(a, 0.f);
    }
    __syncthreads();
    float a = fc2b[t];
#pragma unroll
    for (int j = 0; j < 8; ++j) a += fc2w[t * 8 + j] * rr[j];
    s[n * 128 + t] = 1.f / (1.f + expf(-a));
}

// ---------------------------------------------------------------------------
// Final: out = relu(z * s[n,c] + x), vectorized float4 (standard layouts).
// ---------------------------------------------------------------------------
__global__ void final_kernel(const float* __restrict__ z, const float* __restrict__ x,
                             const float* __restrict__ s, float* __restrict__ out) {
    const int i = blockIdx.x * 256 + threadIdx.x;   // float4 index, 524288 total
    const int plane = i >> 8;                        // 256 float4 per (n,c)
    const float sc = s[plane];
    const float4 zv = ((const float4*)z)[i];
    const float4 xv = ((const float4*)x)[i];
    float4 o;
    o.x = fmaxf(zv.x * sc + xv.x, 0.f);
    o.y = fmaxf(zv.y * sc + xv.y, 0.f);
    o.z = fmaxf(zv.z * sc + xv.z, 0.f);
    o.w = fmaxf(zv.w * sc + xv.w, 0.f);
    ((float4*)out)[i] = o;
}

// ---------------------------------------------------------------------------
extern "C" void kernel_launch(void* const* d_in, const int* in_sizes, int n_in,
                              void* d_out, int out_size, void* d_ws, size_t ws_size,
                              hipStream_t stream) {
    const float* x    = (const float*)d_in[0];
    const float* w1   = (const float*)d_in[1];
    const float* g1   = (const float*)d_in[2];
    const float* b1   = (const float*)d_in[3];
    const float* m1   = (const float*)d_in[4];
    const float* v1   = (const float*)d_in[5];
    const float* w2   = (const float*)d_in[6];
    const float* g2   = (const float*)d_in[7];
    const float* b2   = (const float*)d_in[8];
    const float* m2   = (const float*)d_in[9];
    const float* v2   = (const float*)d_in[10];
    const float* fc1w = (const float*)d_in[11];
    const float* fc1b = (const float*)d_in[12];
    const float* fc2w = (const float*)d_in[13];
    const float* fc2b = (const float*)d_in[14];
    float* out = (float*)d_out;

    float* ws    = (float*)d_ws;
    float* wt1   = ws;                   // 147456 (pair-packed)
    float* wt2   = wt1 + 147456;         // 147456
    float* xpi   = wt2 + 147456;         // 2506752 (interleaved padded x; -> z)
    float* yp    = xpi + 2506752;        // 2506752 (interleaved padded y)
    float* pA    = yp + 2506752;         // 2097152 (split-0 partial, co-fast)
    float* pB    = pA + 2097152;         // 2097152 (split-1 partial, co-fast)
    float* rs    = pB + 2097152;         // 131072 (row partial sums 16x64x128)
    float* s     = rs + 131072;          // 2048
    float* z     = xpi;                  // xpi dead after conv1 -> reuse for z

    wtrans2_kernel<<<1152, 256, 0, stream>>>(w1, wt1, w2, wt2);
    prep_kernel<<<1024, 256, 0, stream>>>(x, xpi, yp);

    dim3 tgrid(32, 16);
    // Conv1 partials -> pA/pB; combine+transpose -> yp (interleaved, +ReLU).
    adder_conv_part<<<2048, 256, 0, stream>>>(xpi, wt1, pA, pB);
    combine_bn_t<true, true ><<<tgrid, 256, 0, stream>>>(pA, pB, g1, b1, m1, v1, yp, rs);
    // Conv2 partials (src = yp) -> pA/pB; combine+transpose -> z + row sums.
    adder_conv_part<<<2048, 256, 0, stream>>>(yp, wt2, pA, pB);
    combine_bn_t<false, false><<<tgrid, 256, 0, stream>>>(pA, pB, g2, b2, m2, v2, z, rs);

    se_kernel<<<16, 128, 0, stream>>>(rs, fc1w, fc1b, fc2w, fc2b, s);
    final_kernel<<<2048, 256, 0, stream>>>(z, x, s, out);
}